// Round 10
// baseline (67.861 us; speedup 1.0000x reference)
//
#include <hip/hip_runtime.h>
#include <stdint.h>

typedef _Float16 half4_t __attribute__((ext_vector_type(4)));
typedef float    floatx4 __attribute__((ext_vector_type(4)));

static constexpr int HW = 128;
static constexpr int DD = 64;

#define GLOAD4O(dst, ptr, o) asm volatile("global_load_dwordx4 %0, %1, off offset:" #o : "=v"(dst) : "v"(ptr) : "memory")
#define GLOAD1O(dst, ptr, o) asm volatile("global_load_dword %0, %1, off offset:" #o   : "=v"(dst) : "v"(ptr) : "memory")
#define WAITV(n) do { asm volatile("s_waitcnt vmcnt(" #n ")" ::: "memory"); \
                      __builtin_amdgcn_sched_barrier(0); } while (0)

// Load one k-tile t of V^T A-fragments: dst[i][dt] = v[16t+4g+i][16dt+lr]
#define LOADT(t_, dst) do { \
    const float* p0_ = vX + (size_t)(16*(t_) + 4*g + 0) * vstr; \
    const float* p1_ = vX + (size_t)(16*(t_) + 4*g + 1) * vstr; \
    const float* p2_ = vX + (size_t)(16*(t_) + 4*g + 2) * vstr; \
    const float* p3_ = vX + (size_t)(16*(t_) + 4*g + 3) * vstr; \
    GLOAD1O(dst[0][0], p0_, 0); GLOAD1O(dst[0][1], p0_, 64); GLOAD1O(dst[0][2], p0_, 128); GLOAD1O(dst[0][3], p0_, 192); \
    GLOAD1O(dst[1][0], p1_, 0); GLOAD1O(dst[1][1], p1_, 64); GLOAD1O(dst[1][2], p1_, 128); GLOAD1O(dst[1][3], p1_, 192); \
    GLOAD1O(dst[2][0], p2_, 0); GLOAD1O(dst[2][1], p2_, 64); GLOAD1O(dst[2][2], p2_, 128); GLOAD1O(dst[2][3], p2_, 192); \
    GLOAD1O(dst[3][0], p3_, 0); GLOAD1O(dst[3][1], p3_, 64); GLOAD1O(dst[3][2], p3_, 128); GLOAD1O(dst[3][3], p3_, 192); \
} while (0)

// Convert a 2-t-tile chunk of raw f32 to half4 A-fragments (compiler packs cvt).
#define CVTC(vf_, c_) do { _Pragma("unroll") for (int tt = 0; tt < 2; ++tt) \
    { _Pragma("unroll") for (int dt = 0; dt < 4; ++dt) { \
        vf_[tt][dt][0] = (_Float16)c_[tt][0][dt]; \
        vf_[tt][dt][1] = (_Float16)c_[tt][1][dt]; \
        vf_[tt][dt][2] = (_Float16)c_[tt][2][dt]; \
        vf_[tt][dt][3] = (_Float16)c_[tt][3][dt]; } } } while (0)

// D^T = V^T (A) x P^T (B): acc[dt] covers d=16dt+4g+i, c(row)=grow.
#define MFMAC(vf_, t0_) do { _Pragma("unroll") for (int tt = 0; tt < 2; ++tt) \
    { _Pragma("unroll") for (int dt = 0; dt < 4; ++dt) \
        acc[dt] = __builtin_amdgcn_mfma_f32_16x16x16f16(vf_[tt][dt], af[(t0_) + tt], acc[dt], 0, 0, 0); } } while (0)

// Block = (b, rc, half h): 64 output rows; 4 independent waves, 16 rows each.
// NO LDS, NO barrier. Per wave: pinned asm loads (atten 8x dwordx4; V^T 128
// scalar dwords in 4 chunks), counted vmcnt pipeline, in-register softmax whose
// A-fragments serve as the MFMA *B* operand (P^T), V^T fragments as A.
// X additionally TOUCH-prefetches a 32KB slab of atten_y into L2/L3 (2 dword
// loads/thread at 64B granule, issued FIRST -> drained by the same counted
// WAITV(32) that waits on atten). The outputs j0_/j1_ are kept ALIVE via an
// empty asm use after that wait: a VMEM load writes its dest VGPR at
// completion, so the register must stay allocated until the load has
// retired (round-9 crash: dead outputs -> reg reuse -> clobbered pointer).
// X: brc=(b,r), rows are c, V=v[b,r,:,:] (k-stride 64).   out = P@V
// Y: brc=(b,c), rows are r, V=v[b,:,c,:] (k-stride 8192); out += (dwordx4 preload).
template<bool IS_Y>
__global__ __launch_bounds__(256, 3)
void axial_attn(const float* __restrict__ atten,
                const float* __restrict__ vsrc,
                const float* __restrict__ shift_p,
                float* __restrict__ out,
                const float* __restrict__ pf)   // X: atten_y base; Y: unused
{
    const int blk  = blockIdx.x;
    const int h    = blk & 1;
    const int brc  = blk >> 1;
    const int b    = brc >> 7;
    const int rc   = brc & 127;
    const int tid  = threadIdx.x;
    const int w    = tid >> 6;
    const int lane = tid & 63;
    const int lr   = lane & 15;
    const int g    = lane >> 4;             // 0..3
    const int grow = h * 64 + w * 16 + lr;  // this lane's softmax/output row

    // ---- X only: issue atten_y touch-prefetch FIRST (oldest in vmcnt queue) ----
    float j0_ = 0.f, j1_ = 0.f;
    if constexpr (!IS_Y) {
        const float* pfp = pf + (size_t)blk * 8192 + (size_t)tid * 32;  // 128B/thread
        asm volatile("global_load_dword %0, %2, off\n\t"
                     "global_load_dword %1, %2, off offset:64"
                     : "=v"(j0_), "=v"(j1_) : "v"(pfp) : "memory");
    }

    // ---- issue: atten (8x dwordx4, rows owned exclusively by this wave) ----
    const float* arow = atten + (size_t)brc * (HW * HW) + (size_t)grow * HW + g * 4;
    floatx4 a0, a1, a2, a3, a4, a5, a6, a7;
    GLOAD4O(a0, arow, 0);   GLOAD4O(a1, arow, 64);  GLOAD4O(a2, arow, 128); GLOAD4O(a3, arow, 192);
    GLOAD4O(a4, arow, 256); GLOAD4O(a5, arow, 320); GLOAD4O(a6, arow, 384); GLOAD4O(a7, arow, 448);

    // ---- issue: V^T chunk 0 (t = 0,1) ----
    const float* vX   = IS_Y ? vsrc + ((size_t)b * HW * HW + rc) * DD + lr
                             : vsrc + (size_t)brc * (HW * DD) + lr;
    const int    vstr = IS_Y ? HW * DD : DD;
    float cA[2][4][4], cB[2][4][4];         // [tt][i][dt], ping-pong
    LOADT(0, cA[0]); LOADT(1, cA[1]);

    // ---- issue: Y out-preload (4x dwordx4) ----
    float* ob = IS_Y ? out + (size_t)b * (HW * HW * DD) + (size_t)grow * (HW * DD) + rc * DD
                     : out + (size_t)brc * (HW * DD) + (size_t)grow * DD;
    floatx4 acc[4];
    if (IS_Y) {
        const float* pb = ob + 4 * g;
        GLOAD4O(acc[0], pb, 0); GLOAD4O(acc[1], pb, 64);
        GLOAD4O(acc[2], pb, 128); GLOAD4O(acc[3], pb, 192);
    } else {
        #pragma unroll
        for (int dt = 0; dt < 4; ++dt) acc[dt] = (floatx4)(0.f);
    }

    // ---- wait: prefetch+atten only; chunk0 [+preload] stay in flight ----
    if constexpr (IS_Y) {
        WAITV(36);
    } else {
        WAITV(32);   // drains 10 oldest: 2 prefetch + 8 atten
        asm volatile("" :: "v"(j0_), "v"(j1_));   // keep-alive until retired
    }

    const float shift = shift_p[0];         // bias cancels in softmax

    // ---- in-register softmax of row `grow` (4 lanes per row, j = 16t+4g+i) ----
    const floatx4 av[8] = {a0, a1, a2, a3, a4, a5, a6, a7};
    float l[32];
    #pragma unroll
    for (int t = 0; t < 8; ++t)
        #pragma unroll
        for (int i = 0; i < 4; ++i) {
            const float d = (float)(16 * t + 4 * g + i - grow);
            l[t * 4 + i] = fmaf(-shift * d, d, av[t][i]);
        }
    float m16[16];
    #pragma unroll
    for (int i = 0; i < 16; ++i) m16[i] = fmaxf(l[i], l[i + 16]);
    #pragma unroll
    for (int s = 8; s >= 1; s >>= 1)
        #pragma unroll
        for (int i = 0; i < s; ++i) m16[i] = fmaxf(m16[i], m16[i + s]);
    float mx = m16[0];
    mx = fmaxf(mx, __shfl_xor(mx, 16));
    mx = fmaxf(mx, __shfl_xor(mx, 32));

    float e[32];
    #pragma unroll
    for (int t = 0; t < 32; ++t) e[t] = __expf(l[t] - mx);
    float s16[16];
    #pragma unroll
    for (int i = 0; i < 16; ++i) s16[i] = e[i] + e[i + 16];
    #pragma unroll
    for (int s = 8; s >= 1; s >>= 1)
        #pragma unroll
        for (int i = 0; i < s; ++i) s16[i] += s16[i + s];
    float sum = s16[0];
    sum += __shfl_xor(sum, 16);
    sum += __shfl_xor(sum, 32);
    const float inv = 1.0f / sum;

    half4_t af[8];                           // P A-frag == P^T B-frag (same lane map)
    #pragma unroll
    for (int t = 0; t < 8; ++t)
        #pragma unroll
        for (int i = 0; i < 4; ++i)
            af[t][i] = (_Float16)(e[4 * t + i] * inv);

    // ---- pipelined V^T chunks: issue next, wait current(32), convert, MFMA ----
    half4_t vf[2][4];
    LOADT(2, cB[0]); LOADT(3, cB[1]);
    WAITV(32);                // chunk0 (+Y preload) done
    CVTC(vf, cA); MFMAC(vf, 0);

    LOADT(4, cA[0]); LOADT(5, cA[1]);
    WAITV(32);                // chunk1 done
    CVTC(vf, cB); MFMAC(vf, 2);

    LOADT(6, cB[0]); LOADT(7, cB[1]);
    WAITV(32);                // chunk2 done
    CVTC(vf, cA); MFMAC(vf, 4);

    WAITV(0);                 // chunk3 done
    CVTC(vf, cB); MFMAC(vf, 6);

    // ---- store: lane holds out[row=grow][d=16dt+4g+i] -> 4x dwordx4 ----
    #pragma unroll
    for (int dt = 0; dt < 4; ++dt)
        *(floatx4*)&ob[16 * dt + 4 * g] = acc[dt];
}

extern "C" void kernel_launch(void* const* d_in, const int* in_sizes, int n_in,
                              void* d_out, int out_size, void* d_ws, size_t ws_size,
                              hipStream_t stream)
{
    // inputs: 0=x (unused), 1=atten_x_full, 2=atten_y_full, 3=value_full, 4=shift, 5=bias (cancels)
    const float* atx   = (const float*)d_in[1];
    const float* aty   = (const float*)d_in[2];
    const float* val   = (const float*)d_in[3];
    const float* shift = (const float*)d_in[4];
    float* out = (float*)d_out;

    axial_attn<false><<<dim3(8 * 128 * 2), dim3(256), 0, stream>>>(atx, val, shift, out, aty);
    axial_attn<true ><<<dim3(8 * 128 * 2), dim3(256), 0, stream>>>(aty, val, shift, out, aty);
}

// Round 11
// 60.017 us; speedup vs baseline: 1.1307x; 1.1307x over previous
//
#include <hip/hip_runtime.h>
#include <stdint.h>

typedef _Float16 half4_t __attribute__((ext_vector_type(4)));
typedef float    floatx4 __attribute__((ext_vector_type(4)));

static constexpr int HW = 128;
static constexpr int DD = 64;

#define GLOAD4O(dst, ptr, o) asm volatile("global_load_dwordx4 %0, %1, off offset:" #o : "=v"(dst) : "v"(ptr) : "memory")
#define GLOAD1O(dst, ptr, o) asm volatile("global_load_dword %0, %1, off offset:" #o   : "=v"(dst) : "v"(ptr) : "memory")
#define WAITV(n) do { asm volatile("s_waitcnt vmcnt(" #n ")" ::: "memory"); \
                      __builtin_amdgcn_sched_barrier(0); } while (0)

// Load one k-tile t of V^T A-fragments: dst[i][dt] = v[16t+4g+i][16dt+lr]
// (16 wave-level dword loads; each covers 4x64B segments per 16-lane group)
#define LOADT(t_, dst) do { \
    const float* p0_ = vX + (size_t)(16*(t_) + 4*g + 0) * vstr; \
    const float* p1_ = vX + (size_t)(16*(t_) + 4*g + 1) * vstr; \
    const float* p2_ = vX + (size_t)(16*(t_) + 4*g + 2) * vstr; \
    const float* p3_ = vX + (size_t)(16*(t_) + 4*g + 3) * vstr; \
    GLOAD1O(dst[0][0], p0_, 0); GLOAD1O(dst[0][1], p0_, 64); GLOAD1O(dst[0][2], p0_, 128); GLOAD1O(dst[0][3], p0_, 192); \
    GLOAD1O(dst[1][0], p1_, 0); GLOAD1O(dst[1][1], p1_, 64); GLOAD1O(dst[1][2], p1_, 128); GLOAD1O(dst[1][3], p1_, 192); \
    GLOAD1O(dst[2][0], p2_, 0); GLOAD1O(dst[2][1], p2_, 64); GLOAD1O(dst[2][2], p2_, 128); GLOAD1O(dst[2][3], p2_, 192); \
    GLOAD1O(dst[3][0], p3_, 0); GLOAD1O(dst[3][1], p3_, 64); GLOAD1O(dst[3][2], p3_, 128); GLOAD1O(dst[3][3], p3_, 192); \
} while (0)

// One k-tile: convert raw f32 chunk buffer -> half4 A-fragments (compiler packs cvt).
#define CVT1(vf_, c_) do { _Pragma("unroll") for (int dt = 0; dt < 4; ++dt) { \
        vf_[dt][0] = (_Float16)c_[0][dt]; \
        vf_[dt][1] = (_Float16)c_[1][dt]; \
        vf_[dt][2] = (_Float16)c_[2][dt]; \
        vf_[dt][3] = (_Float16)c_[3][dt]; } } while (0)

// D^T = V^T (A) x P^T (B): acc[dt] covers d=16dt+4g+i, c(row)=grow.
#define MFMA1(vf_, t_) do { _Pragma("unroll") for (int dt = 0; dt < 4; ++dt) \
        acc[dt] = __builtin_amdgcn_mfma_f32_16x16x16f16(vf_[dt], af[(t_)], acc[dt], 0, 0, 0); } while (0)

// Block = (b, rc, half h): 64 output rows; 4 independent waves, 16 rows each.
// NO LDS, NO barrier. Pinned asm loads + counted-vmcnt pipeline:
//   queue: atten(8) [Y: +preload(4)] c0 c1 | WAITV(32/36) | c2 c3 | softmax |
//   ph0..7: WAITV(48,48,48,48,48,32,16,0), CVT+4xMFMA, ph0-3 re-issue c4..c7
//   -> each chunk's use is ~4 phases after issue; in-flight ~16KB/wave in the
//   MFMA section (was ~1KB -> latency-bound at 2.8 TB/s in r8).
// In-register softmax (A-frag layout) serves as the MFMA B operand (P^T);
// V^T fragments as A.  Logits computed in place over atten regs (VGPR cap).
// X: brc=(b,r), rows are c, V=v[b,r,:,:] (k-stride 64).   out = P@V
// Y: brc=(b,c), rows are r, V=v[b,:,c,:] (k-stride 8192); out += (dwordx4 preload).
template<bool IS_Y>
__global__ __launch_bounds__(256, 3)
void axial_attn(const float* __restrict__ atten,
                const float* __restrict__ vsrc,
                const float* __restrict__ shift_p,
                float* __restrict__ out)
{
    const int blk  = blockIdx.x;
    const int h    = blk & 1;
    const int brc  = blk >> 1;
    const int b    = brc >> 7;
    const int rc   = brc & 127;
    const int tid  = threadIdx.x;
    const int w    = tid >> 6;
    const int lane = tid & 63;
    const int lr   = lane & 15;
    const int g    = lane >> 4;             // 0..3
    const int grow = h * 64 + w * 16 + lr;  // this lane's softmax/output row

    // ---- issue: atten (8x dwordx4, oldest in queue) ----
    const float* arow = atten + (size_t)brc * (HW * HW) + (size_t)grow * HW + g * 4;
    floatx4 a0, a1, a2, a3, a4, a5, a6, a7;
    GLOAD4O(a0, arow, 0);   GLOAD4O(a1, arow, 64);  GLOAD4O(a2, arow, 128); GLOAD4O(a3, arow, 192);
    GLOAD4O(a4, arow, 256); GLOAD4O(a5, arow, 320); GLOAD4O(a6, arow, 384); GLOAD4O(a7, arow, 448);

    const float* vX   = IS_Y ? vsrc + ((size_t)b * HW * HW + rc) * DD + lr
                             : vsrc + (size_t)brc * (HW * DD) + lr;
    const int    vstr = IS_Y ? HW * DD : DD;

    // ---- issue: Y out-preload (4x dwordx4), then V chunks 0,1 ----
    float* ob = IS_Y ? out + (size_t)b * (HW * HW * DD) + (size_t)grow * (HW * DD) + rc * DD
                     : out + (size_t)brc * (HW * DD) + (size_t)grow * DD;
    floatx4 acc[4];
    if (IS_Y) {
        const float* pb = ob + 4 * g;
        GLOAD4O(acc[0], pb, 0); GLOAD4O(acc[1], pb, 64);
        GLOAD4O(acc[2], pb, 128); GLOAD4O(acc[3], pb, 192);
    } else {
        #pragma unroll
        for (int dt = 0; dt < 4; ++dt) acc[dt] = (floatx4)(0.f);
    }

    float cb0[4][4], cb1[4][4], cb2[4][4], cb3[4][4];   // rotating chunk buffers
    LOADT(0, cb0); LOADT(1, cb1);

    // ---- wait: atten only (X: 8 drained, c0,c1=32 left; Y: pre+c0,c1=36 left) ----
    if constexpr (IS_Y) { WAITV(36); } else { WAITV(32); }

    // ---- issue: V chunks 2,3 (flight covered by softmax) ----
    LOADT(2, cb2); LOADT(3, cb3);

    const float shift = shift_p[0];         // bias cancels in softmax

    // ---- in-register softmax of row `grow` (logits in place over atten regs) ----
    floatx4 av[8] = {a0, a1, a2, a3, a4, a5, a6, a7};
    #pragma unroll
    for (int t = 0; t < 8; ++t)
        #pragma unroll
        for (int i = 0; i < 4; ++i) {
            const float d = (float)(16 * t + 4 * g + i - grow);
            av[t][i] = fmaf(-shift * d, d, av[t][i]);
        }
    float m16[16];
    #pragma unroll
    for (int i = 0; i < 16; ++i) m16[i] = fmaxf(av[i >> 2][i & 3], av[4 + (i >> 2)][i & 3]);
    #pragma unroll
    for (int s = 8; s >= 1; s >>= 1)
        #pragma unroll
        for (int i = 0; i < s; ++i) m16[i] = fmaxf(m16[i], m16[i + s]);
    float mx = m16[0];
    mx = fmaxf(mx, __shfl_xor(mx, 16));
    mx = fmaxf(mx, __shfl_xor(mx, 32));

    float e[32];
    #pragma unroll
    for (int t = 0; t < 8; ++t)
        #pragma unroll
        for (int i = 0; i < 4; ++i) e[t * 4 + i] = __expf(av[t][i] - mx);
    float s16[16];
    #pragma unroll
    for (int i = 0; i < 16; ++i) s16[i] = e[i] + e[i + 16];
    #pragma unroll
    for (int s = 8; s >= 1; s >>= 1)
        #pragma unroll
        for (int i = 0; i < s; ++i) s16[i] += s16[i + s];
    float sum = s16[0];
    sum += __shfl_xor(sum, 16);
    sum += __shfl_xor(sum, 32);
    const float inv = 1.0f / sum;

    half4_t af[8];                           // P A-frag == P^T B-frag (same lane map)
    #pragma unroll
    for (int t = 0; t < 8; ++t)
        #pragma unroll
        for (int i = 0; i < 4; ++i)
            af[t][i] = (_Float16)(e[4 * t + i] * inv);

    // ---- 8 phases: wait one chunk, CVT+MFMA it, re-issue buffer (ph0-3) ----
    half4_t vf[4];
    WAITV(48); CVT1(vf, cb0); MFMA1(vf, 0); LOADT(4, cb0);   // drains c0 (+Y pre)
    WAITV(48); CVT1(vf, cb1); MFMA1(vf, 1); LOADT(5, cb1);   // drains c1
    WAITV(48); CVT1(vf, cb2); MFMA1(vf, 2); LOADT(6, cb2);   // drains c2
    WAITV(48); CVT1(vf, cb3); MFMA1(vf, 3); LOADT(7, cb3);   // drains c3
    WAITV(48); CVT1(vf, cb0); MFMA1(vf, 4);                  // drains c4
    WAITV(32); CVT1(vf, cb1); MFMA1(vf, 5);                  // drains c5
    WAITV(16); CVT1(vf, cb2); MFMA1(vf, 6);                  // drains c6
    WAITV(0);  CVT1(vf, cb3); MFMA1(vf, 7);                  // drains c7

    // ---- store: lane holds out[row=grow][d=16dt+4g+i] -> 4x dwordx4 ----
    #pragma unroll
    for (int dt = 0; dt < 4; ++dt)
        *(floatx4*)&ob[16 * dt + 4 * g] = acc[dt];
}

extern "C" void kernel_launch(void* const* d_in, const int* in_sizes, int n_in,
                              void* d_out, int out_size, void* d_ws, size_t ws_size,
                              hipStream_t stream)
{
    // inputs: 0=x (unused), 1=atten_x_full, 2=atten_y_full, 3=value_full, 4=shift, 5=bias (cancels)
    const float* atx   = (const float*)d_in[1];
    const float* aty   = (const float*)d_in[2];
    const float* val   = (const float*)d_in[3];
    const float* shift = (const float*)d_in[4];
    float* out = (float*)d_out;

    axial_attn<false><<<dim3(8 * 128 * 2), dim3(256), 0, stream>>>(atx, val, shift, out);
    axial_attn<true ><<<dim3(8 * 128 * 2), dim3(256), 0, stream>>>(aty, val, shift, out);
}